// Round 1
// baseline (464.046 us; speedup 1.0000x reference)
//
#include <hip/hip_runtime.h>
#include <cmath>
#include <cstdint>

// HashGrid encoder (instant-NGP style).
// B=524288 points, L=16 levels, F=2 feats, MAX_PARAMS=2^19.
// One thread per (point, level): tid = b*16 + l.
// out viewed as float2[B*16]: out2[b*16 + l] == out2[tid]  -> coalesced.

#define NLEVELS 16
#define BPOINTS 524288

struct LevelMeta {
    float    scale[NLEVELS];    // fp32 cast of double scale (matches reference)
    uint32_t size[NLEVELS];     // hashmap size (entries)
    uint32_t offset[NLEVELS];   // offset in float2 units (== element offset)
    uint32_t mul_y[NLEVELS];    // dense: r      ; fast: 2654435761
    uint32_t mul_z[NLEVELS];    // dense: r*r    ; fast: 805459861
    uint32_t fast[NLEVELS];     // 1 if spatial hash level
};

__global__ __launch_bounds__(256) void hashenc_kernel(
    const float*  __restrict__ pos,
    const float2* __restrict__ tbl,
    float2*       __restrict__ out,
    LevelMeta meta)
{
    const int t = blockIdx.x * 256 + threadIdx.x;     // [0, B*16)
    const int b = t >> 4;
    const int l = t & 15;

    const float x = pos[b * 3 + 0];
    const float y = pos[b * 3 + 1];
    const float z = pos[b * 3 + 2];

    const float s = meta.scale[l];
    // match numpy exactly: mul then add, no fma contraction
    const float px = __fadd_rn(__fmul_rn(x, s), 0.5f);
    const float py = __fadd_rn(__fmul_rn(y, s), 0.5f);
    const float pz = __fadd_rn(__fmul_rn(z, s), 0.5f);

    const float gx = floorf(px), gy = floorf(py), gz = floorf(pz);
    const float fx = px - gx,    fy = py - gy,    fz = pz - gz;

    const uint32_t ix = (uint32_t)gx, iy = (uint32_t)gy, iz = (uint32_t)gz;

    const uint32_t size  = meta.size[l];
    const uint32_t off   = meta.offset[l];
    const uint32_t my    = meta.mul_y[l];
    const uint32_t mz    = meta.mul_z[l];
    const bool     fast  = meta.fast[l] != 0;
    const uint32_t mask  = size - 1u;                 // valid only for fast (size=2^19)

    // Per-dim hash contributions; both dense and fast are linear in the coord:
    //   dense: c*stride, (c+1)*stride = c*stride + stride
    //   fast : c*prime,  (c+1)*prime  = c*prime  + prime
    const uint32_t hx0 = ix,       hx1 = ix + 1u;
    const uint32_t hy0 = iy * my,  hy1 = hy0 + my;
    const uint32_t hz0 = iz * mz,  hz1 = hz0 + mz;

    const float wx0 = 1.0f - fx, wx1 = fx;
    const float wy0 = 1.0f - fy, wy1 = fy;
    const float wz0 = 1.0f - fz, wz1 = fz;

    float o0 = 0.0f, o1 = 0.0f;

#pragma unroll
    for (int c = 0; c < 8; ++c) {
        const uint32_t hxv = (c & 1) ? hx1 : hx0;
        const uint32_t hyv = (c & 2) ? hy1 : hy0;
        const uint32_t hzv = (c & 4) ? hz1 : hz0;

        uint32_t h;
        if (fast) {
            h = (hxv ^ hyv ^ hzv) & mask;
        } else {
            h = (hxv + hyv + hzv) % size;             // uint32 wrap-add then mod, matches ref
        }

        const float wxv = (c & 1) ? wx1 : wx0;
        const float wyv = (c & 2) ? wy1 : wy0;
        const float wzv = (c & 4) ? wz1 : wz0;
        const float w = __fmul_rn(__fmul_rn(wxv, wyv), wzv);  // ((wx*wy)*wz), jnp.prod order

        const float2 f = tbl[off + h];
        o0 = __fmaf_rn(w, f.x, o0);
        o1 = __fmaf_rn(w, f.y, o1);
    }

    // nontemporal 8B store: 64MB write-only stream, keep L2 for the table
    union { float2 f2; unsigned long long u64; } u;
    u.f2 = make_float2(o0, o1);
    __builtin_nontemporal_store(u.u64, (unsigned long long*)&out[t]);
}

static void fill_meta(LevelMeta& m)
{
    const double PLS = 1.3195079565048218;
    const uint32_t P1 = 2654435761u, P2 = 805459861u;
    const long long MAXP = 1ll << 19;
    long long off = 0;
    for (int i = 0; i < NLEVELS; ++i) {
        const double scale_d = 16.0 * pow(PLS, (double)i) - 1.0;
        const long long r = (long long)ceil(scale_d) + 1;
        const long long full = r * r * r;
        const long long aligned = ((full + 7) / 8) * 8;
        const long long p = aligned < MAXP ? aligned : MAXP;
        const bool fast = full > p;
        m.scale[i]  = (float)scale_d;
        m.size[i]   = (uint32_t)p;
        m.offset[i] = (uint32_t)off;          // float2 units == element units
        m.mul_y[i]  = fast ? P1 : (uint32_t)r;
        m.mul_z[i]  = fast ? P2 : (uint32_t)(r * r);
        m.fast[i]   = fast ? 1u : 0u;
        off += p;
    }
}

extern "C" void kernel_launch(void* const* d_in, const int* in_sizes, int n_in,
                              void* d_out, int out_size, void* d_ws, size_t ws_size,
                              hipStream_t stream)
{
    const float*  positions = (const float*)d_in[0];
    const float2* table     = (const float2*)d_in[1];
    float2*       out       = (float2*)d_out;

    LevelMeta m;
    fill_meta(m);

    const int total  = BPOINTS * NLEVELS;     // 8,388,608 threads
    const int block  = 256;
    const int grid   = total / block;         // 32768

    hashenc_kernel<<<grid, block, 0, stream>>>(positions, table, out, m);
}

// Round 2
// 213.597 us; speedup vs baseline: 2.1725x; 2.1725x over previous
//
#include <hip/hip_runtime.h>
#include <cmath>
#include <cstdint>

// Instant-NGP hash-grid encoder, level-phased for L2 residency.
// B=524288 points, L=16 levels, F=2, fast-level tables are 4MB each (= per-XCD L2).
//
// Kernel A (gather): grid (B/256, 16). blockIdx.y = level -> all concurrently
//   resident blocks share 1-2 levels -> each XCD L2 holds the live level table.
//   Writes level-major ws[l*B + b] (coalesced).
// Kernel B (transpose): ws[l][b] -> out[b*16 + l] via LDS 16x64 tiles.

#define NLEVELS 16
#define BPOINTS 524288

struct LevelMeta {
    float    scale[NLEVELS];
    uint32_t size[NLEVELS];     // entries
    uint32_t offset[NLEVELS];   // float2 units
    uint32_t mul_y[NLEVELS];    // dense: r    ; fast: 2654435761
    uint32_t mul_z[NLEVELS];    // dense: r*r  ; fast: 805459861
    uint32_t fast[NLEVELS];
};

__device__ __forceinline__ void encode_one(
    const float* __restrict__ pos, const float2* __restrict__ tbl,
    int b, int l, const LevelMeta& meta, float& o0, float& o1)
{
    const float x = pos[b * 3 + 0];
    const float y = pos[b * 3 + 1];
    const float z = pos[b * 3 + 2];

    const float s = meta.scale[l];
    const float px = __fadd_rn(__fmul_rn(x, s), 0.5f);
    const float py = __fadd_rn(__fmul_rn(y, s), 0.5f);
    const float pz = __fadd_rn(__fmul_rn(z, s), 0.5f);

    const float gx = floorf(px), gy = floorf(py), gz = floorf(pz);
    const float fx = px - gx,    fy = py - gy,    fz = pz - gz;

    const uint32_t ix = (uint32_t)gx, iy = (uint32_t)gy, iz = (uint32_t)gz;

    const uint32_t size  = meta.size[l];
    const uint32_t off   = meta.offset[l];
    const uint32_t my    = meta.mul_y[l];
    const uint32_t mz    = meta.mul_z[l];
    const bool     fastl = meta.fast[l] != 0;
    const uint32_t mask  = size - 1u;            // fast levels: size == 2^19

    const uint32_t hx0 = ix,      hx1 = ix + 1u;
    const uint32_t hy0 = iy * my, hy1 = hy0 + my;
    const uint32_t hz0 = iz * mz, hz1 = hz0 + mz;

    const float wx0 = 1.0f - fx, wx1 = fx;
    const float wy0 = 1.0f - fy, wy1 = fy;
    const float wz0 = 1.0f - fz, wz1 = fz;

    uint32_t idx[8];
#pragma unroll
    for (int c = 0; c < 8; ++c) {
        const uint32_t hxv = (c & 1) ? hx1 : hx0;
        const uint32_t hyv = (c & 2) ? hy1 : hy0;
        const uint32_t hzv = (c & 4) ? hz1 : hz0;
        uint32_t h;
        if (fastl) {
            h = (hxv ^ hyv ^ hzv) & mask;
        } else {
            // dense: h = x + y*r + z*r^2 < 2*size  ->  exact mod via one subtract
            h = hxv + hyv + hzv;
            h = (h >= size) ? (h - size) : h;
        }
        idx[c] = off + h;
    }

    // all 8 gathers in flight before any use (ILP=8)
    float2 f[8];
#pragma unroll
    for (int c = 0; c < 8; ++c) f[c] = tbl[idx[c]];

    o0 = 0.0f; o1 = 0.0f;
#pragma unroll
    for (int c = 0; c < 8; ++c) {
        const float wxv = (c & 1) ? wx1 : wx0;
        const float wyv = (c & 2) ? wy1 : wy0;
        const float wzv = (c & 4) ? wz1 : wz0;
        const float w = __fmul_rn(__fmul_rn(wxv, wyv), wzv);
        o0 = __fmaf_rn(w, f[c].x, o0);
        o1 = __fmaf_rn(w, f[c].y, o1);
    }
}

// ---- Kernel A: phased gather, level-major ws output ----
__global__ __launch_bounds__(256) void hashenc_gather(
    const float*  __restrict__ pos,
    const float2* __restrict__ tbl,
    float2*       __restrict__ ws,
    LevelMeta meta)
{
    const int l = blockIdx.y;                       // wave-uniform level -> SGPR meta
    const int b = blockIdx.x * 256 + threadIdx.x;
    float o0, o1;
    encode_one(pos, tbl, b, l, meta, o0, o1);
    ws[l * BPOINTS + b] = make_float2(o0, o1);      // coalesced
}

// ---- Kernel B: transpose ws[l][b] -> out[b*16+l], LDS 16x64 tiles ----
__global__ __launch_bounds__(256) void hashenc_transpose(
    const float2* __restrict__ ws,
    float2*       __restrict__ out)
{
    __shared__ float2 tile[NLEVELS][65];            // +1 pad breaks bank conflicts
    const int b0  = blockIdx.x * 64;
    const int tid = threadIdx.x;

#pragma unroll
    for (int k = 0; k < 4; ++k) {
        const int idx = k * 256 + tid;              // [0,1024)
        const int l = idx >> 6, j = idx & 63;
        tile[l][j] = ws[l * BPOINTS + b0 + j];      // 512B/row coalesced
    }
    __syncthreads();
#pragma unroll
    for (int k = 0; k < 4; ++k) {
        const int idx = k * 256 + tid;              // flat out index within tile
        const int j = idx >> 4, l = idx & 15;
        union { float2 f2; unsigned long long u64; } u;
        u.f2 = tile[l][j];
        __builtin_nontemporal_store(u.u64,
            (unsigned long long*)&out[b0 * NLEVELS + idx]);  // 2KB contiguous
    }
}

// ---- Fallback (point-major, direct write) if workspace too small ----
__global__ __launch_bounds__(256) void hashenc_direct(
    const float*  __restrict__ pos,
    const float2* __restrict__ tbl,
    float2*       __restrict__ out,
    LevelMeta meta)
{
    const int t = blockIdx.x * 256 + threadIdx.x;
    const int b = t >> 4;
    const int l = t & 15;
    float o0, o1;
    encode_one(pos, tbl, b, l, meta, o0, o1);
    union { float2 f2; unsigned long long u64; } u;
    u.f2 = make_float2(o0, o1);
    __builtin_nontemporal_store(u.u64, (unsigned long long*)&out[t]);
}

static void fill_meta(LevelMeta& m)
{
    const double PLS = 1.3195079565048218;
    const uint32_t P1 = 2654435761u, P2 = 805459861u;
    const long long MAXP = 1ll << 19;
    long long off = 0;
    for (int i = 0; i < NLEVELS; ++i) {
        const double scale_d = 16.0 * pow(PLS, (double)i) - 1.0;
        const long long r = (long long)ceil(scale_d) + 1;
        const long long full = r * r * r;
        const long long aligned = ((full + 7) / 8) * 8;
        const long long p = aligned < MAXP ? aligned : MAXP;
        const bool fast = full > p;
        m.scale[i]  = (float)scale_d;
        m.size[i]   = (uint32_t)p;
        m.offset[i] = (uint32_t)off;
        m.mul_y[i]  = fast ? P1 : (uint32_t)r;
        m.mul_z[i]  = fast ? P2 : (uint32_t)(r * r);
        m.fast[i]   = fast ? 1u : 0u;
        off += p;
    }
}

extern "C" void kernel_launch(void* const* d_in, const int* in_sizes, int n_in,
                              void* d_out, int out_size, void* d_ws, size_t ws_size,
                              hipStream_t stream)
{
    const float*  positions = (const float*)d_in[0];
    const float2* table     = (const float2*)d_in[1];
    float2*       out       = (float2*)d_out;

    LevelMeta m;
    fill_meta(m);

    const size_t ws_need = (size_t)BPOINTS * NLEVELS * sizeof(float2);  // 64 MB
    if (ws_size >= ws_need) {
        dim3 grid(BPOINTS / 256, NLEVELS);
        hashenc_gather<<<grid, 256, 0, stream>>>(positions, table, (float2*)d_ws, m);
        hashenc_transpose<<<BPOINTS / 64, 256, 0, stream>>>((const float2*)d_ws, out);
    } else {
        hashenc_direct<<<(BPOINTS * NLEVELS) / 256, 256, 0, stream>>>(positions, table, out, m);
    }
}